// Round 7
// baseline (326.742 us; speedup 1.0000x reference)
//
#include <hip/hip_runtime.h>

#define HH 512
#define WW 512
#define NPIX (HH*WW)      // 2^18
#define BATCH 16
#define NIMG 32           // 16 ref + 16 tgt

typedef unsigned char uchar;
typedef unsigned long long u64;

// DPP lane shifts (VALU pipe, no LDS): wave_shl:1 = 0x130 (lane l reads l+1),
// wave_shr:1 = 0x138 (lane l reads l-1), bound_ctrl=true -> zero-fill at edge.
template<int CTRL>
__device__ __forceinline__ float dppf(float v) {
    return __int_as_float(__builtin_amdgcn_update_dpp(
        0, __float_as_int(v), CTRL, 0xF, 0xF, true));
}
template<int CTRL>
__device__ __forceinline__ int dppi(int v) {
    return __builtin_amdgcn_update_dpp(0, v, CTRL, 0xF, 0xF, true);
}
#define SHUP(v)  dppf<0x130>(v)   // lane l <- lane l+1 (0 at lane 63)
#define SHDN(v)  dppf<0x138>(v)   // lane l <- lane l-1 (0 at lane 0)
#define SHUPI(v) dppi<0x130>(v)
#define SHDNI(v) dppi<0x138>(v)

__inline__ __device__ float wave_reduce(float v) {
#pragma unroll
    for (int o = 32; o > 0; o >>= 1) v += __shfl_down(v, o);
    return v;
}

// ---------------- Stage 1: luminance (one-shot, float4) + acc zeroing ------
__global__ __launch_bounds__(256) void k_lum(const float4* __restrict__ ref,
                                             const float4* __restrict__ tgt,
                                             float4* __restrict__ lum,
                                             double* __restrict__ acc) {
    int idx = blockIdx.x * 256 + threadIdx.x;     // NIMG * NPIX/4 threads
    if (idx < NIMG * 4) acc[idx] = 0.0;
    int img = idx >> 16;                          // NPIX/4 = 65536
    int p4 = idx & 65535;
    const float4* src = (img < BATCH) ? (ref + (size_t)img * 3 * 65536)
                                      : (tgt + (size_t)(img - BATCH) * 3 * 65536);
    float4 r = src[p4];
    float4 g = src[65536 + p4];
    float4 b = src[131072 + p4];
    float4 o;
    o.x = 0.299f * r.x + 0.587f * g.x + 0.114f * b.x;
    o.y = 0.299f * r.y + 0.587f * g.y + 0.114f * b.y;
    o.z = 0.299f * r.z + 0.587f * g.z + 0.114f * b.z;
    o.w = 0.299f * r.w + 0.587f * g.w + 0.114f * b.w;
    lum[idx] = o;
}

// ---- Stages 2+3+4: wave-pipelined strip, 16 output rows per wave ----------
// One wave = 52 output cols x 16 output rows (was 32) -> 10240 waves / 2560
// blocks: 2x wave count to fill the TLP-starved machine (round-6 counters:
// VALUBusy 40%, occupancy ~5 waves/CU, dur invariant across instruction-mix
// changes => residency-limited). Horizontal E-dilation now per-lane DPP ORs
// (bit-identical incl. zero-fill edges) removing the ballot->SGPR->64b-shift
// round-trip from the serial e->hb->pp chain. Count ballots kept (off-path).
__global__ __launch_bounds__(256) void k_strip(const float* __restrict__ lum,
                                               uchar* __restrict__ Mo_g,
                                               double* __restrict__ acc) {
    int lane = threadIdx.x & 63;
    int gw = blockIdx.x * 4 + (threadIdx.x >> 6);   // 0..10239
    int img = gw / 320;                             // 10 sx * 32 sy
    int rem = gw - img * 320;
    int sy = rem / 10;
    int sx = rem - sy * 10;
    int r0 = sy << 4;          // first output row (16-row strips)
    int c0 = sx * 52;
    int col = c0 + lane - 6;
    bool colok = (unsigned)col < WW;

    const float* Lp = lum + (size_t)img * NPIX;
    uchar* Mo = Mo_g + (size_t)img * NPIX;

    // rolling lum triples: slot0=oldest(L-3) .. slot3=newest(L)
    float tm0 = 0, tm1 = 0, tm2 = 0, tm3 = 0;
    float tc0 = 0, tc1 = 0, tc2 = 0, tc3 = 0;
    float tp0 = 0, tp1 = 0, tp2 = 0, tp3 = 0;
    unsigned eb = 0, hb = 0, pbm = 0, vbm = 0;

    // ---- explicit prefetch pipeline (depth 2) ----
    float preA = (((unsigned)(r0 - 6) < HH) && colok) ? Lp[(size_t)(r0 - 6) * WW + col] : 0.0f;
    float preB = (((unsigned)(r0 - 5) < HH) && colok) ? Lp[(size_t)(r0 - 5) * WW + col] : 0.0f;

#define ROTATE3() { \
    tm0 = tm1; tc0 = tc1; tp0 = tp1; \
    tm1 = tm2; tc1 = tc2; tp1 = tp2; \
    tm2 = tm3; tc2 = tc3; tp2 = tp3; }

#define LOADROW(Lr) { \
    ROTATE3(); \
    float ln = preA; preA = preB; \
    { int rr = (Lr) + 2; \
      preB = (((unsigned)rr < HH) && colok) ? Lp[(size_t)rr * WW + col] : 0.0f; } \
    tc3 = ln; tm3 = SHDN(ln); tp3 = SHUP(ln); }

#define LOADROW_NP(Lr) { \
    ROTATE3(); \
    float ln = preA; preA = preB; \
    tc3 = ln; tm3 = SHDN(ln); tp3 = SHUP(ln); }

// E for row Lr-1. Horizontal dilation (cols +-2) via DPP ORs: identical to
// the old (ebal<<2)>>lane & 0x1F incl. zero-fill at lanes 0,1,62,63.
#define SOBEL_E(Lr) { \
    float gx = (tp1 - tm1) + 2.0f * (tp2 - tm2) + (tp3 - tm3); \
    float gy = (tm3 + 2.0f * tc3 + tp3) - (tm1 + 2.0f * tc1 + tp1); \
    float grad = sqrtf(gx * gx + gy * gy + 1e-12f); \
    bool e = (grad > 0.1f) && colok && ((unsigned)((Lr) - 1) < HH); \
    int ei = e ? 1 : 0; \
    int u1 = SHUPI(ei); int d1 = SHDNI(ei); \
    int u2 = SHUPI(u1); int d2 = SHDNI(d1); \
    int he = ei | u1 | d1 | u2 | d2; \
    eb = (eb << 1) | (unsigned)ei; \
    hb = (hb << 1) | (unsigned)he; }

// sliding 7-window sum centered at lane:
// a = y[l]+y[l+1]; b = a[l]+a[l+2] = y[l..l+3]; out = b[l] + b[l-3] - y[l]
#define SLIDE7(yv, out) { \
    float a_ = (yv) + SHUP(yv); \
    float t_ = SHUP(SHUP(a_)); \
    float b_ = a_ + t_; \
    float d_ = SHDN(SHDN(SHDN(b_))); \
    out = b_ + d_ - (yv); }

    // ---- pre-roll: rows r0-6, r0-5 ----
    for (int q = 0; q < 2; ++q) { int Lr = r0 - 6 + q; LOADROW(Lr); }
    // ---- warm: rows r0-4..r0-1 (E/hE only) ----
    for (int q = 0; q < 4; ++q) { int Lr = r0 - 4 + q; LOADROW(Lr); SOBEL_E(Lr); }

    // ---- steady: 22 iterations (j=0..21), ring mod 7 ----
    float r1p[7], r2p[7], r1v[7], r2v[7];
    unsigned rcn[7];
    unsigned cnt_acc = 0;
    float a1p = 0, a2p = 0, a1v = 0, a2v = 0;
    float c0a = 0, c1a = 0, c2a = 0, c3a = 0;

#define STEP(jv, u, LOADM) { \
    int j = (jv); \
    int Lr = r0 + j; \
    LOADM(Lr); \
    SOBEL_E(Lr); \
    int m = Lr - 3; \
    bool ed = (hb & 0x1Fu) != 0; \
    bool e3 = ((eb >> 2) & 1u) != 0; \
    bool mrowok = (unsigned)m < HH; \
    bool pp = ed && !e3 && mrowok && colok; \
    bool vv = (!ed) && mrowok && colok; \
    u64 pb = __ballot(pp); \
    u64 vb = __ballot(vv); \
    pbm = (pbm << 1) | (pp ? 1u : 0u); \
    vbm = (vbm << 1) | (vv ? 1u : 0u); \
    float x = tc0; \
    float xq = x * x; \
    float y1p = pp ? x  : 0.0f; \
    float y2p = pp ? xq : 0.0f; \
    float y1v = vv ? x  : 0.0f; \
    float y2v = vv ? xq : 0.0f; \
    float s1p, s2p, s1v, s2v; \
    SLIDE7(y1p, s1p) \
    SLIDE7(y2p, s2p) \
    SLIDE7(y1v, s1v) \
    SLIDE7(y2v, s2v) \
    unsigned pw = (unsigned)((pb << 3) >> lane) & 0x7Fu; \
    unsigned vw = (unsigned)((vb << 3) >> lane) & 0x7Fu; \
    unsigned cnt_new = (unsigned)__popc(pw) | ((unsigned)__popc(vw) << 8); \
    if (j >= 7) { \
        cnt_acc -= rcn[u]; \
        a1p -= r1p[u]; a2p -= r2p[u]; a1v -= r1v[u]; a2v -= r2v[u]; \
    } \
    cnt_acc += cnt_new; \
    a1p += s1p; a2p += s2p; a1v += s1v; a2v += s2v; \
    rcn[u] = cnt_new; r1p[u] = s1p; r2p[u] = s2p; r1v[u] = s1v; r2v[u] = s2v; \
    if (j >= 3 && j <= 18) { \
        if (lane >= 6 && lane <= 57 && colok) \
            Mo[(size_t)m * WW + col] = (uchar)(pp ? 1 : 0); \
    } \
    if (j >= 6 && j <= 21) { \
        float mp0 = (float)((pbm >> 3) & 1u); \
        float mb0 = (float)((vbm >> 3) & 1u); \
        if (lane < 6 || lane > 57) { mp0 = 0.0f; mb0 = 0.0f; } \
        float cpf = (float)(cnt_acc & 0xFFu); \
        float cvf = (float)((cnt_acc >> 8) & 0xFFu); \
        float rCp = __builtin_amdgcn_rcpf(fmaxf(cpf, 1.0f)); \
        float meanp = a1p * rCp; \
        float varp = fmaxf(a2p * rCp - meanp * meanp, 0.0f); \
        float rCb = __builtin_amdgcn_rcpf(fmaxf(cvf, 1.0f)); \
        float meanb = a1v * rCb; \
        float varb = fmaxf(a2v * rCb - meanb * meanb, 0.0f); \
        c0a += varp * mp0; c1a += mp0; \
        c2a += varb * mb0; c3a += mb0; \
    } }

    for (int o6 = 0; o6 < 2; ++o6) {
#pragma unroll
        for (int u = 0; u < 7; ++u) {
            STEP(o6 * 7 + u, u, LOADROW)
        }
    }
    // tail: j=14..19 still prefetch (rows r0+16..r0+21); j=20,21 consume only
    STEP(14, 0, LOADROW)
    STEP(15, 1, LOADROW)
    STEP(16, 2, LOADROW)
    STEP(17, 3, LOADROW)
    STEP(18, 4, LOADROW)
    STEP(19, 5, LOADROW)
    STEP(20, 6, LOADROW_NP)
    STEP(21, 0, LOADROW_NP)

#undef STEP
#undef SLIDE7
#undef SOBEL_E
#undef LOADROW
#undef LOADROW_NP
#undef ROTATE3

    c0a = wave_reduce(c0a); c1a = wave_reduce(c1a);
    c2a = wave_reduce(c2a); c3a = wave_reduce(c3a);
    if (lane == 0) {
        atomicAdd(&acc[img * 4 + 0], (double)c0a);
        atomicAdd(&acc[img * 4 + 1], (double)c1a);
        atomicAdd(&acc[img * 4 + 2], (double)c2a);
        atomicAdd(&acc[img * 4 + 3], (double)c3a);
    }
}

// ---------------- Stage 5: output with fused flags (verified) --------------
__global__ __launch_bounds__(256) void k_out(const uchar4* __restrict__ M,
                                             const double* __restrict__ acc,
                                             float4* __restrict__ out) {
    __shared__ float sf[2];
    int idx = blockIdx.x * 256 + threadIdx.x;   // BATCH * NPIX/4 threads
    int b = idx >> 16;                          // constant within a block
    if (threadIdx.x == 0) {
        const double* a = acc + (size_t)b * 4;
        double vp = a[0] / fmax(a[1], 1.0);
        double vb = a[2] / fmax(a[3], 1.0);
        sf[0] = ((vp / (vb + 1e-12)) > 2.0) ? 1.0f : 0.0f;
        const double* a2 = acc + (size_t)(b + BATCH) * 4;
        double vp2 = a2[0] / fmax(a2[1], 1.0);
        double vb2 = a2[2] / fmax(a2[3], 1.0);
        sf[1] = ((vp2 / (vb2 + 1e-12)) > 2.0) ? 1.0f : 0.0f;
    }
    __syncthreads();
    float fr = sf[0], ft = sf[1];
    int p = idx & 65535;
    uchar4 mr = M[(size_t)b * 65536 + p];
    uchar4 mt = M[(size_t)(b + BATCH) * 65536 + p];
    float4 o;
    o.x = fmaxf((mt.x ? ft : 0.0f) - (mr.x ? fr : 0.0f), 0.0f);
    o.y = fmaxf((mt.y ? ft : 0.0f) - (mr.y ? fr : 0.0f), 0.0f);
    o.z = fmaxf((mt.z ? ft : 0.0f) - (mr.z ? fr : 0.0f), 0.0f);
    o.w = fmaxf((mt.w ? ft : 0.0f) - (mr.w ? fr : 0.0f), 0.0f);
    out[idx] = o;
}

extern "C" void kernel_launch(void* const* d_in, const int* in_sizes, int n_in,
                              void* d_out, int out_size, void* d_ws, size_t ws_size,
                              hipStream_t stream) {
    const float* ref = (const float*)d_in[0];
    const float* tgt = (const float*)d_in[1];
    float* out = (float*)d_out;

    char* ws = (char*)d_ws;
    double* acc = (double*)ws;                                 // 32*4 doubles
    uchar* Mo = (uchar*)(ws + 2048);                           // 8 MB prox bytes
    float* lum = (float*)(ws + 2048 + (size_t)NIMG * NPIX);    // 32 MB

    int nAll = NIMG * NPIX;          // 8388608
    k_lum<<<nAll / 4 / 256, 256, 0, stream>>>((const float4*)ref, (const float4*)tgt,
                                              (float4*)lum, acc);
    k_strip<<<2560, 256, 0, stream>>>(lum, Mo, acc);   // 10240 waves
    k_out<<<BATCH * NPIX / 4 / 256, 256, 0, stream>>>((const uchar4*)Mo, acc, (float4*)out);
}

// Round 8
// 212.728 us; speedup vs baseline: 1.5360x; 1.5360x over previous
//
#include <hip/hip_runtime.h>

#define HH 512
#define WW 512
#define NPIX (HH*WW)      // 2^18
#define BATCH 16
#define NIMG 32           // 16 ref + 16 tgt

typedef unsigned char uchar;
typedef unsigned long long u64;

// DPP lane shifts (VALU pipe, no LDS): wave_shl:1 = 0x130 (lane l reads l+1),
// wave_shr:1 = 0x138 (lane l reads l-1), bound_ctrl=true -> zero-fill at edge.
template<int CTRL>
__device__ __forceinline__ float dppf(float v) {
    return __int_as_float(__builtin_amdgcn_update_dpp(
        0, __float_as_int(v), CTRL, 0xF, 0xF, true));
}
template<int CTRL>
__device__ __forceinline__ int dppi(int v) {
    return __builtin_amdgcn_update_dpp(0, v, CTRL, 0xF, 0xF, true);
}
#define SHUP(v)  dppf<0x130>(v)   // lane l <- lane l+1 (0 at lane 63)
#define SHDN(v)  dppf<0x138>(v)   // lane l <- lane l-1 (0 at lane 0)
#define SHUPI(v) dppi<0x130>(v)
#define SHDNI(v) dppi<0x138>(v)

__inline__ __device__ float wave_reduce(float v) {
#pragma unroll
    for (int o = 32; o > 0; o >>= 1) v += __shfl_down(v, o);
    return v;
}

// ---------------- Stage 1: luminance (one-shot, float4) + acc zeroing ------
__global__ __launch_bounds__(256) void k_lum(const float4* __restrict__ ref,
                                             const float4* __restrict__ tgt,
                                             float4* __restrict__ lum,
                                             double* __restrict__ acc) {
    int idx = blockIdx.x * 256 + threadIdx.x;     // NIMG * NPIX/4 threads
    if (idx < NIMG * 4) acc[idx] = 0.0;
    int img = idx >> 16;                          // NPIX/4 = 65536
    int p4 = idx & 65535;
    const float4* src = (img < BATCH) ? (ref + (size_t)img * 3 * 65536)
                                      : (tgt + (size_t)(img - BATCH) * 3 * 65536);
    float4 r = src[p4];
    float4 g = src[65536 + p4];
    float4 b = src[131072 + p4];
    float4 o;
    o.x = 0.299f * r.x + 0.587f * g.x + 0.114f * b.x;
    o.y = 0.299f * r.y + 0.587f * g.y + 0.114f * b.y;
    o.z = 0.299f * r.z + 0.587f * g.z + 0.114f * b.z;
    o.w = 0.299f * r.w + 0.587f * g.w + 0.114f * b.w;
    lum[idx] = o;
}

// ---- Stages 2+3+4: wave-pipelined strip (r6 geometry: 32 rows/wave) -------
// Round-8 change, single variable vs the verified 104-us r6 kernel:
//   (a) prefetch ring depth 2 -> 4 (preA..preD): 2x outstanding loads/wave.
//   (b) rolling state slimmed 12 -> 4 regs (tc0..tc3); the shifted rows are
//       recomputed in SOBEL via the invariant tm_k=SHDN(tc_k), tp_k=SHUP(tc_k)
//       (exact under rotation) -> pays for (a) with VGPR to spare.
// Everything else (masks, SLIDE7 sums, ring, outputs) is bit-identical to r6.
__global__ __launch_bounds__(256) void k_strip(const float* __restrict__ lum,
                                               uchar* __restrict__ Mo_g,
                                               double* __restrict__ acc) {
    int lane = threadIdx.x & 63;
    int gw = blockIdx.x * 4 + (threadIdx.x >> 6);   // 0..5119
    int img = gw / 160;                             // 10 sx * 16 sy
    int rem = gw - img * 160;
    int sy = rem / 10;
    int sx = rem - sy * 10;
    int r0 = sy << 5;          // first output row (32-row strips)
    int c0 = sx * 52;
    int col = c0 + lane - 6;
    bool colok = (unsigned)col < WW;

    const float* Lp = lum + (size_t)img * NPIX;
    uchar* Mo = Mo_g + (size_t)img * NPIX;

    // rolling lum rows: tc0=oldest(L-3) .. tc3=newest(L)
    float tc0 = 0, tc1 = 0, tc2 = 0, tc3 = 0;
    unsigned eb = 0, hb = 0, pbm = 0, vbm = 0;

#define GLOAD(rr) ((((unsigned)(rr) < HH) && colok) ? Lp[(size_t)(rr) * WW + col] : 0.0f)

    // ---- prefetch ring, depth 4 ----
    float preA = GLOAD(r0 - 6);
    float preB = GLOAD(r0 - 5);
    float preC = GLOAD(r0 - 4);
    float preD = GLOAD(r0 - 3);

#define LOADROW(Lr) { \
    tc0 = tc1; tc1 = tc2; tc2 = tc3; \
    float ln = preA; preA = preB; preB = preC; preC = preD; \
    preD = GLOAD((Lr) + 4); \
    tc3 = ln; }

#define LOADROW_NP(Lr) { \
    tc0 = tc1; tc1 = tc2; tc2 = tc3; \
    float ln = preA; preA = preB; preB = preC; preC = preD; \
    tc3 = ln; }

// E for row Lr-1. tm_k/tp_k recomputed from tc_k (exact). Horizontal
// dilation (cols +-2) via DPP ORs, zero-fill identical to ballot form.
#define SOBEL_E(Lr) { \
    float tm1 = SHDN(tc1), tp1 = SHUP(tc1); \
    float tm2 = SHDN(tc2), tp2 = SHUP(tc2); \
    float tm3 = SHDN(tc3), tp3 = SHUP(tc3); \
    float gx = (tp1 - tm1) + 2.0f * (tp2 - tm2) + (tp3 - tm3); \
    float gy = (tm3 + 2.0f * tc3 + tp3) - (tm1 + 2.0f * tc1 + tp1); \
    float grad = sqrtf(gx * gx + gy * gy + 1e-12f); \
    bool e = (grad > 0.1f) && colok && ((unsigned)((Lr) - 1) < HH); \
    int ei = e ? 1 : 0; \
    int u1 = SHUPI(ei); int d1 = SHDNI(ei); \
    int u2 = SHUPI(u1); int d2 = SHDNI(d1); \
    int he = ei | u1 | d1 | u2 | d2; \
    eb = (eb << 1) | (unsigned)ei; \
    hb = (hb << 1) | (unsigned)he; }

// sliding 7-window sum centered at lane:
// a = y[l]+y[l+1]; b = a[l]+a[l+2] = y[l..l+3]; out = b[l] + b[l-3] - y[l]
#define SLIDE7(yv, out) { \
    float a_ = (yv) + SHUP(yv); \
    float t_ = SHUP(SHUP(a_)); \
    float b_ = a_ + t_; \
    float d_ = SHDN(SHDN(SHDN(b_))); \
    out = b_ + d_ - (yv); }

    // ---- pre-roll: rows r0-6, r0-5 ----
    for (int q = 0; q < 2; ++q) { int Lr = r0 - 6 + q; LOADROW(Lr); }
    // ---- warm: rows r0-4..r0-1 (E/hE only) ----
    for (int q = 0; q < 4; ++q) { int Lr = r0 - 4 + q; LOADROW(Lr); SOBEL_E(Lr); }

    // ---- steady: 38 iterations (j=0..37), ring mod 7 ----
    float r1p[7], r2p[7], r1v[7], r2v[7];
    unsigned rcn[7];
    unsigned cnt_acc = 0;
    float a1p = 0, a2p = 0, a1v = 0, a2v = 0;
    float c0a = 0, c1a = 0, c2a = 0, c3a = 0;

#define STEP(jv, u, LOADM) { \
    int j = (jv); \
    int Lr = r0 + j; \
    LOADM(Lr); \
    SOBEL_E(Lr); \
    int m = Lr - 3; \
    bool ed = (hb & 0x1Fu) != 0; \
    bool e3 = ((eb >> 2) & 1u) != 0; \
    bool mrowok = (unsigned)m < HH; \
    bool pp = ed && !e3 && mrowok && colok; \
    bool vv = (!ed) && mrowok && colok; \
    u64 pb = __ballot(pp); \
    u64 vb = __ballot(vv); \
    pbm = (pbm << 1) | (pp ? 1u : 0u); \
    vbm = (vbm << 1) | (vv ? 1u : 0u); \
    float x = tc0; \
    float xq = x * x; \
    float y1p = pp ? x  : 0.0f; \
    float y2p = pp ? xq : 0.0f; \
    float y1v = vv ? x  : 0.0f; \
    float y2v = vv ? xq : 0.0f; \
    float s1p, s2p, s1v, s2v; \
    SLIDE7(y1p, s1p) \
    SLIDE7(y2p, s2p) \
    SLIDE7(y1v, s1v) \
    SLIDE7(y2v, s2v) \
    unsigned pw = (unsigned)((pb << 3) >> lane) & 0x7Fu; \
    unsigned vw = (unsigned)((vb << 3) >> lane) & 0x7Fu; \
    unsigned cnt_new = (unsigned)__popc(pw) | ((unsigned)__popc(vw) << 8); \
    if (j >= 7) { \
        cnt_acc -= rcn[u]; \
        a1p -= r1p[u]; a2p -= r2p[u]; a1v -= r1v[u]; a2v -= r2v[u]; \
    } \
    cnt_acc += cnt_new; \
    a1p += s1p; a2p += s2p; a1v += s1v; a2v += s2v; \
    rcn[u] = cnt_new; r1p[u] = s1p; r2p[u] = s2p; r1v[u] = s1v; r2v[u] = s2v; \
    if (j >= 3 && j <= 34) { \
        if (lane >= 6 && lane <= 57 && colok) \
            Mo[(size_t)m * WW + col] = (uchar)(pp ? 1 : 0); \
    } \
    if (j >= 6 && j <= 37) { \
        float mp0 = (float)((pbm >> 3) & 1u); \
        float mb0 = (float)((vbm >> 3) & 1u); \
        if (lane < 6 || lane > 57) { mp0 = 0.0f; mb0 = 0.0f; } \
        float cpf = (float)(cnt_acc & 0xFFu); \
        float cvf = (float)((cnt_acc >> 8) & 0xFFu); \
        float rCp = __builtin_amdgcn_rcpf(fmaxf(cpf, 1.0f)); \
        float meanp = a1p * rCp; \
        float varp = fmaxf(a2p * rCp - meanp * meanp, 0.0f); \
        float rCb = __builtin_amdgcn_rcpf(fmaxf(cvf, 1.0f)); \
        float meanb = a1v * rCb; \
        float varb = fmaxf(a2v * rCb - meanb * meanb, 0.0f); \
        c0a += varp * mp0; c1a += mp0; \
        c2a += varb * mb0; c3a += mb0; \
    } }

    for (int o6 = 0; o6 < 4; ++o6) {
#pragma unroll
        for (int u = 0; u < 7; ++u) {
            STEP(o6 * 7 + u, u, LOADROW)
        }
    }
    // j=28..33 still load (rows r0+32..r0+37); j=34..37 consume only
    STEP(28, 0, LOADROW)
    STEP(29, 1, LOADROW)
    STEP(30, 2, LOADROW)
    STEP(31, 3, LOADROW)
    STEP(32, 4, LOADROW)
    STEP(33, 5, LOADROW)
    STEP(34, 6, LOADROW_NP)
    STEP(35, 0, LOADROW_NP)
    STEP(36, 1, LOADROW_NP)
    STEP(37, 2, LOADROW_NP)

#undef STEP
#undef SLIDE7
#undef SOBEL_E
#undef LOADROW
#undef LOADROW_NP
#undef GLOAD

    c0a = wave_reduce(c0a); c1a = wave_reduce(c1a);
    c2a = wave_reduce(c2a); c3a = wave_reduce(c3a);
    if (lane == 0) {
        atomicAdd(&acc[img * 4 + 0], (double)c0a);
        atomicAdd(&acc[img * 4 + 1], (double)c1a);
        atomicAdd(&acc[img * 4 + 2], (double)c2a);
        atomicAdd(&acc[img * 4 + 3], (double)c3a);
    }
}

// ---------------- Stage 5: output with fused flags (verified) --------------
__global__ __launch_bounds__(256) void k_out(const uchar4* __restrict__ M,
                                             const double* __restrict__ acc,
                                             float4* __restrict__ out) {
    __shared__ float sf[2];
    int idx = blockIdx.x * 256 + threadIdx.x;   // BATCH * NPIX/4 threads
    int b = idx >> 16;                          // constant within a block
    if (threadIdx.x == 0) {
        const double* a = acc + (size_t)b * 4;
        double vp = a[0] / fmax(a[1], 1.0);
        double vb = a[2] / fmax(a[3], 1.0);
        sf[0] = ((vp / (vb + 1e-12)) > 2.0) ? 1.0f : 0.0f;
        const double* a2 = acc + (size_t)(b + BATCH) * 4;
        double vp2 = a2[0] / fmax(a2[1], 1.0);
        double vb2 = a2[2] / fmax(a2[3], 1.0);
        sf[1] = ((vp2 / (vb2 + 1e-12)) > 2.0) ? 1.0f : 0.0f;
    }
    __syncthreads();
    float fr = sf[0], ft = sf[1];
    int p = idx & 65535;
    uchar4 mr = M[(size_t)b * 65536 + p];
    uchar4 mt = M[(size_t)(b + BATCH) * 65536 + p];
    float4 o;
    o.x = fmaxf((mt.x ? ft : 0.0f) - (mr.x ? fr : 0.0f), 0.0f);
    o.y = fmaxf((mt.y ? ft : 0.0f) - (mr.y ? fr : 0.0f), 0.0f);
    o.z = fmaxf((mt.z ? ft : 0.0f) - (mr.z ? fr : 0.0f), 0.0f);
    o.w = fmaxf((mt.w ? ft : 0.0f) - (mr.w ? fr : 0.0f), 0.0f);
    out[idx] = o;
}

extern "C" void kernel_launch(void* const* d_in, const int* in_sizes, int n_in,
                              void* d_out, int out_size, void* d_ws, size_t ws_size,
                              hipStream_t stream) {
    const float* ref = (const float*)d_in[0];
    const float* tgt = (const float*)d_in[1];
    float* out = (float*)d_out;

    char* ws = (char*)d_ws;
    double* acc = (double*)ws;                                 // 32*4 doubles
    uchar* Mo = (uchar*)(ws + 2048);                           // 8 MB prox bytes
    float* lum = (float*)(ws + 2048 + (size_t)NIMG * NPIX);    // 32 MB

    int nAll = NIMG * NPIX;          // 8388608
    k_lum<<<nAll / 4 / 256, 256, 0, stream>>>((const float4*)ref, (const float4*)tgt,
                                              (float4*)lum, acc);
    k_strip<<<1280, 256, 0, stream>>>(lum, Mo, acc);   // 5120 waves
    k_out<<<BATCH * NPIX / 4 / 256, 256, 0, stream>>>((const uchar4*)Mo, acc, (float4*)out);
}